// Round 9
// baseline (428.060 us; speedup 1.0000x reference)
//
#include <hip/hip_runtime.h>
#include <hip/hip_bf16.h>
#include <stdint.h>

// Problem constants (B=4, S=2048, IN=4096, OUT=4096, FP=256)
// Harness dtype contract (verified R3): reference float16 tensors are
// delivered/read as FLOAT32; int8 -> int32; output read as float32.
#define N_TOK 8192
#define IN_F  4096
#define OUT_F 4096
#define FP_F  256
#define INT_F 3840
#define PROW  1920    // packed int4 bytes per row (INT_F/2)

typedef int    v4i   __attribute__((ext_vector_type(4)));
typedef int    v16i  __attribute__((ext_vector_type(16)));
typedef float  v16f  __attribute__((ext_vector_type(16)));
typedef __bf16 bf16x8 __attribute__((ext_vector_type(8)));

// ---------------- workspace layout (bytes) ----------------
// A (activations): packed nibbles, row-major [n][1920], 32B per half-tile
//   (ht=0..59), slot-swizzled: phys8 = s8 ^ ((n>>2)&3).
// B (weights): UNPACKED biased int8, k-major per half-tile:
//   [60 ht][4 slots][4096 rows][16B]  (ht stride 262144, slot stride 65536)
// fpx/wfp: bf16 row-major [n][256] with 2-slot swizzle per 32B chunk:
//   phys half = h ^ ((row>>2)&1).
#define WS_QP   0u            // 15,728,640
#define WS_WP   15728640u     // 15,728,640
#define WS_FPX  31457280u     //  4,194,304
#define WS_WFP  35651584u     //  2,097,152
#define WS_F1   37748736u     // [N_TOK] float: scale
#define WS_F2   37781504u     // [N_TOK] float: -8*sumc*scale
#define WS_F3   37814272u     // [N_TOK] float: row min
#define WS_NEED 37847040u

// A nibble packing: global 16-code group G = 4*ht + s8 holds codes
// i = 16G..16G+15; byte b = c[16G+b] | c[16G+b+8]<<4, stored at
// n*1920 + ht*32 + (s8 ^ ((n>>2)&3))*8 + b.
// Biased-code algebra (verified passing): D = sum (q+8)(w+8);
// out = (D*sc + f2)*ws + f3*rw + bias + bf16_outlier_dot.
// All swizzles use row bits 2.. only -> serve every 128-aligned tile.

__global__ __launch_bounds__(256) void zero_out_kernel(uint4* __restrict__ o) {
  o[(size_t)blockIdx.x * 256 + threadIdx.x] = uint4{0, 0, 0, 0};
}

// ---------------- fused prep kernel ----------------
// grid = [0,2048): quant, 4 tokens/block (1 wave/token, no __syncthreads)
//      | [2048,17408): conv_w (unpacked k-major) | [17408,18432): conv_wfp
__global__ __launch_bounds__(256, 4) void prep_kernel(
    const float* __restrict__ x,
    const int* __restrict__ int_idx, const int* __restrict__ fp_idx,
    const int* __restrict__ int_w, const float* __restrict__ fp_w,
    uint8_t* __restrict__ qp, uint8_t* __restrict__ wp,
    __hip_bfloat16* __restrict__ fpx, __hip_bfloat16* __restrict__ wfp,
    float* __restrict__ f1, float* __restrict__ f2, float* __restrict__ f3) {
  __shared__ uint2 qb[960];               // 4 waves x 1920B packed staging

  int tid = threadIdx.x;
  int blk = blockIdx.x;

  if (blk >= 2048) {
    int pb = blk - 2048;
    if (pb < 15360) {
      // ---- conv_w: 4 int32 weights -> 4 biased byte codes, k-major ----
      int t = pb * 256 + tid;                 // u32 index, 4096*960 total
      int r = t / 960, u = t % 960;           // u: 4-code group within row
      const int* src = int_w + (size_t)r * INT_F + u * 4;
      int4 w4 = *(const int4*)src;
      uint32_t pk = (uint32_t)((w4.x + 8) & 15) |
                    (uint32_t)((w4.y + 8) & 15) << 8 |
                    (uint32_t)((w4.z + 8) & 15) << 16 |
                    (uint32_t)((w4.w + 8) & 15) << 24;
      // codes 4u..4u+3: global group S = u>>2; ht = S>>2 = u>>4; s8 = S&3
      *(uint32_t*)(wp + (size_t)(u >> 4) * 262144 + (size_t)((u >> 2) & 3) * 65536
                      + (size_t)r * 16 + (u & 3) * 4) = pk;
    } else {
      // ---- conv_wfp: fp_weight f32 -> bf16, 2-slot swizzled dest ----
      int t = (pb - 15360) * 256 + tid;
      int i = t * 4;
      int r = i >> 8, c = i & 255;
      float4 v = *(const float4*)(fp_w + i);
      __hip_bfloat16 b[4] = {__float2bfloat16(v.x), __float2bfloat16(v.y),
                             __float2bfloat16(v.z), __float2bfloat16(v.w)};
      int cs = (c & ~8) | (((((c) >> 3) & 1) ^ ((r >> 2) & 1)) << 3);
      *(uint2*)(wfp + (size_t)r * 256 + cs) = *(const uint2*)b;
    }
    return;
  }

  // ---- quant: one WAVE per token; lane l owns values i = l + 64k, k<60 ----
  int wave = tid >> 6, l = tid & 63;
  int n = blk * 4 + wave;
  const float* xr = x + (size_t)n * IN_F;

  float v[60];
  float lmn = 1e30f, lmx = -1e30f;
#pragma unroll
  for (int k = 0; k < 60; k++) {
    v[k] = xr[int_idx[l + 64 * k]];
    lmn = fminf(lmn, v[k]);
    lmx = fmaxf(lmx, v[k]);
  }
  // fp outlier gather (4 per lane); 2-slot bf16 swizzle
  {
    int swF = (n >> 2) & 1;
#pragma unroll
    for (int j = 0; j < 4; j++) {
      int c = l + 64 * j;
      int cs = (c & ~8) | ((((c >> 3) & 1) ^ swF) << 3);
      fpx[(size_t)n * FP_F + cs] = __float2bfloat16(xr[fp_idx[c]]);
    }
  }

  // wave-wide butterfly min/max -> every lane holds the result
#pragma unroll
  for (int off = 32; off > 0; off >>= 1) {
    lmn = fminf(lmn, __shfl_xor(lmn, off, 64));
    lmx = fmaxf(lmx, __shfl_xor(lmx, off, 64));
  }
  float mn = lmn;
  float sc = fmaxf((lmx - mn) / 15.0f, 1e-8f);   // IEEE f32 div, matches ref
  float inv = 1.0f / sc;
  if (l == 0) { f1[n] = sc; f3[n] = mn; }

  uint8_t* qbw = (uint8_t*)qb + wave * 1920;
  int swA = (n >> 2) & 3;                 // baked A swizzle (uniform per wave)
  float lsum = 0.0f;
#pragma unroll
  for (int k = 0; k < 60; k++) {
    // value index i = l + 64k; code c in [0,15]
    float c = fminf(fmaxf(rintf((v[k] - mn) * inv), 0.0f), 15.0f);
    lsum += c;
    float ch = __shfl_down(c, 8, 64);      // partner value i+8 (same wave)
    if ((l & 15) < 8) {                    // low-nibble owner writes byte
      // i = l+64k: ht = k, s8 = l>>4, byte = l&7
      int pos = k * 32 + (((l >> 4) ^ swA) << 3) + (l & 7);
      qbw[pos] = (uint8_t)((uint32_t)c | ((uint32_t)ch << 4));
    }
  }
#pragma unroll
  for (int off = 32; off > 0; off >>= 1) lsum += __shfl_xor(lsum, off, 64);
  if (l == 0) f2[n] = -8.0f * lsum * sc;   // exact: integer-valued f32 sums

  // coalesced store of the wave's 1920B (240 uint2); wave-local, no barrier
  const uint2* qbu = qb + wave * 240;
#pragma unroll
  for (int r = 0; r < 4; r++) {
    int i = l + 64 * r;
    if (i < 240) *(uint2*)(qp + (size_t)n * PROW + i * 8) = qbu[i];
  }
}

__device__ inline v4i unpack_nib(uint2 u) {
  v4i r;
  r[0] = (int)(u.x & 0x0F0F0F0Fu);
  r[1] = (int)(u.y & 0x0F0F0F0Fu);
  r[2] = (int)((u.x >> 4) & 0x0F0F0F0Fu);
  r[3] = (int)((u.y >> 4) & 0x0F0F0F0Fu);
  return r;
}

__device__ __forceinline__ void gl16(const void* g, void* l) {
  __builtin_amdgcn_global_load_lds(
      (const __attribute__((address_space(1))) void*)g,
      (__attribute__((address_space(3))) void*)l, 16, 0, 0);
}

// Kernel 3 v12: R8's hybrid (A packed/unpack-in-reg, B unpacked k-major,
// counted vmcnt) shrunk to BK=64 so LDS = 24KB -> 4 blocks/CU target
// (regs 64 VGPR + 64 AGPR = 128 = 4 waves/SIMD). Evidence: per-block MFMA
// duty is ~18% (R8) and concurrency is the product's other factor; this
// maximizes blocks while keeping R8's cheaper inner loop. Cost: 120 int
// barriers (2x R8) -- the one axis never isolated at multi-block.
// bf16 phase: 16 rounds of K=16 in 8KB dbuf buffers.
__global__ __launch_bounds__(256, 4) void gemm_kernel(
    const uint8_t* __restrict__ qp, const uint8_t* __restrict__ wp,
    const __hip_bfloat16* __restrict__ fpx, const __hip_bfloat16* __restrict__ wfp,
    const float* __restrict__ f1, const float* __restrict__ f2,
    const float* __restrict__ f3,
    const float* __restrict__ wscale, const float* __restrict__ reduced,
    const float* __restrict__ bias, float* __restrict__ out) {
  __shared__ int4 lds4[1536];             // 24 KB = 2 x (A 4K + B 8K)
  int8_t* lds = (int8_t*)lds4;

  int tid = threadIdx.x;
  int wave = tid >> 6, lane = tid & 63;
  int wm = wave >> 1, wn = wave & 1;
  int blk = blockIdx.x;
  int tileM = ((blk & 7) << 3) | ((blk >> 3) & 7);   // XCD-aware swizzle
  int tileN = blk >> 6;
  int n0 = tileM * 128, o0 = tileN * 128;

  union { v16i i; v16f f; } acc[2][2];
#pragma unroll
  for (int mi = 0; mi < 2; mi++)
#pragma unroll
    for (int ni = 0; ni < 2; ni++)
#pragma unroll
      for (int e = 0; e < 16; e++) acc[mi][ni].i[e] = 0;

  int m = lane & 31, kg = lane >> 5;

  // A staging (packed, 4KB/step): thread covers row tid>>1, 16B half tid&1
  int rowA = tid >> 1, hA = tid & 1;
  const uint8_t* gA = qp + (size_t)(n0 + rowA) * PROW + hA * 16;
  // B staging (unpacked k-major, 8KB/step): chunks tid (slots 0/1) and
  // tid+256 (slots 2/3); dest is lane-linear tid*16 within each region.
  const uint8_t* gB0 = wp + (size_t)(tid >> 7) * 65536 + (size_t)(o0 + (tid & 127)) * 16;
  const uint8_t* gB1 = gB0 + 2 * 65536;
  int lA = tid * 16, lB0 = 4096 + tid * 16, lB1 = 8192 + tid * 16;

#define STAGE_INT(buf, ht) do {                                      \
    gl16(gA + (ht) * 32, lds + (buf) + lA);                          \
    gl16(gB0 + (size_t)(ht) * 262144, lds + (buf) + lB0);            \
    gl16(gB1 + (size_t)(ht) * 262144, lds + (buf) + lB1);            \
  } while (0)

  auto compute_int = [&](const int8_t* lb) {
#pragma unroll
    for (int ks = 0; ks < 2; ks++) {
      int s8 = ks * 2 + kg;
      v4i a[2], b[2];
#pragma unroll
      for (int mi = 0; mi < 2; mi++) {
        int row = wm * 64 + mi * 32 + m;
        a[mi] = unpack_nib(*(const uint2*)&lb[row * 32 + ((s8 ^ ((row >> 2) & 3)) * 8)]);
      }
#pragma unroll
      for (int ni = 0; ni < 2; ni++) {
        int row = wn * 64 + ni * 32 + m;
        b[ni] = *(const v4i*)&lb[4096 + s8 * 2048 + row * 16];   // raw, no unpack
      }
#pragma unroll
      for (int mi = 0; mi < 2; mi++)
#pragma unroll
        for (int ni = 0; ni < 2; ni++)
          acc[mi][ni].i = __builtin_amdgcn_mfma_i32_32x32x32_i8(
              a[mi], b[ni], acc[mi][ni].i, 0, 0, 0);
    }
  };

  // ---------------- int4 phase: 60 half-tiles of K=64, dbuf ----------------
  STAGE_INT(0, 0);
#pragma unroll 1
  for (int t = 0; t < 60; t += 2) {
    STAGE_INT(12288, t + 1);
    asm volatile("s_waitcnt vmcnt(3)" ::: "memory");   // buf0's 3 loads done
    __builtin_amdgcn_s_barrier();
    compute_int(lds);
    __builtin_amdgcn_s_barrier();
    if (t + 2 < 60) {
      STAGE_INT(0, t + 2);
      asm volatile("s_waitcnt vmcnt(3)" ::: "memory"); // buf1's 3 loads done
    } else {
      asm volatile("s_waitcnt vmcnt(0)" ::: "memory");
    }
    __builtin_amdgcn_s_barrier();
    compute_int(lds + 12288);
    __builtin_amdgcn_s_barrier();
  }

  // bf16 staging pointers: round kr covers 32B chunk at byte 32*kr of each
  // 512B row; thread covers row tid>>1, 16B half tid&1 (phys, pre-swizzled)
  const uint8_t* fxb = (const uint8_t*)fpx;
  const uint8_t* fwb = (const uint8_t*)wfp;
  const uint8_t* gFA = fxb + (size_t)(n0 + rowA) * 512 + hA * 16;
  const uint8_t* gFB = fwb + (size_t)(o0 + rowA) * 512 + hA * 16;

#define STAGE_BF(buf, kr) do {                                   \
    gl16(gFA + (kr) * 32, lds + (buf) + lA);                     \
    gl16(gFB + (kr) * 32, lds + (buf) + 4096 + lA);              \
  } while (0)

  // stage bf16 round 0 now; latency hides under the dequant fold below
  STAGE_BF(0, 0);

  // -------- in-place dequant fold: acc.i -> acc.f (exact, D < 2^24) --------
  int col = lane & 31, rb4 = (lane >> 5) * 4;
  float cws[2], crw[2], cbs[2];
#pragma unroll
  for (int ni = 0; ni < 2; ni++) {
    int o = o0 + wn * 64 + ni * 32 + col;
    cws[ni] = wscale[o]; crw[ni] = reduced[o]; cbs[ni] = bias[o];
  }
#pragma unroll
  for (int mi = 0; mi < 2; mi++) {
#pragma unroll
    for (int reg = 0; reg < 16; reg++) {
      int row = (reg & 3) + 8 * (reg >> 2) + rb4;
      int n = n0 + wm * 64 + mi * 32 + row;
      float a1 = f1[n], a2 = f2[n], a3 = f3[n];
      float d0 = (float)acc[mi][0].i[reg];
      float d1 = (float)acc[mi][1].i[reg];
      acc[mi][0].f[reg] = (d0 * a1 + a2) * cws[0] + a3 * crw[0] + cbs[0];
      acc[mi][1].f[reg] = (d1 * a1 + a2) * cws[1] + a3 * crw[1] + cbs[1];
    }
  }

  auto compute_bf = [&](const int8_t* lb) {
    bf16x8 a[2], b[2];
#pragma unroll
    for (int mi = 0; mi < 2; mi++) {
      int row = wm * 64 + mi * 32 + m;
      a[mi] = *(const bf16x8*)&lb[row * 32 + ((kg ^ ((row >> 2) & 1)) * 16)];
    }
#pragma unroll
    for (int ni = 0; ni < 2; ni++) {
      int row = wn * 64 + ni * 32 + m;
      b[ni] = *(const bf16x8*)&lb[4096 + row * 32 + ((kg ^ ((row >> 2) & 1)) * 16)];
    }
#pragma unroll
    for (int mi = 0; mi < 2; mi++)
#pragma unroll
      for (int ni = 0; ni < 2; ni++)
        acc[mi][ni].f = __builtin_amdgcn_mfma_f32_32x32x16_bf16(
            a[mi], b[ni], acc[mi][ni].f, 0, 0, 0);
  };

  // ---------- bf16 outlier phase: 16 rounds of K=16, 8KB dbuf ----------
#pragma unroll 1
  for (int kr = 0; kr < 16; kr += 2) {
    STAGE_BF(8192, kr + 1);
    asm volatile("s_waitcnt vmcnt(2)" ::: "memory");
    __builtin_amdgcn_s_barrier();
    compute_bf(lds);
    __builtin_amdgcn_s_barrier();
    if (kr + 2 < 16) {
      STAGE_BF(0, kr + 2);
      asm volatile("s_waitcnt vmcnt(2)" ::: "memory");
    } else {
      asm volatile("s_waitcnt vmcnt(0)" ::: "memory");
    }
    __builtin_amdgcn_s_barrier();
    compute_bf(lds + 8192);
    __builtin_amdgcn_s_barrier();
  }
#undef STAGE_INT
#undef STAGE_BF

  // ---------------- store (f32) ----------------
#pragma unroll
  for (int mi = 0; mi < 2; mi++) {
#pragma unroll
    for (int ni = 0; ni < 2; ni++) {
      int o = o0 + wn * 64 + ni * 32 + col;
#pragma unroll
      for (int reg = 0; reg < 16; reg++) {
        int row = (reg & 3) + 8 * (reg >> 2) + rb4;
        int n = n0 + wm * 64 + mi * 32 + row;
        out[(size_t)n * OUT_F + o] = acc[mi][ni].f[reg];
      }
    }
  }
}

extern "C" void kernel_launch(void* const* d_in, const int* in_sizes, int n_in,
                              void* d_out, int out_size, void* d_ws, size_t ws_size,
                              hipStream_t stream) {
  const float* x     = (const float*)d_in[0];
  const int*   int_w = (const int*)d_in[1];
  const float* fp_w  = (const float*)d_in[2];
  const float* bias  = (const float*)d_in[3];
  const float* wsc   = (const float*)d_in[4];
  const float* red   = (const float*)d_in[5];
  const int*   iidx  = (const int*)d_in[6];
  const int*   fidx  = (const int*)d_in[7];
  float*       out   = (float*)d_out;

  if (ws_size < (size_t)WS_NEED) {
    zero_out_kernel<<<out_size / 1024, 256, 0, stream>>>((uint4*)d_out);
    return;
  }

  uint8_t* ws = (uint8_t*)d_ws;
  uint8_t*        qp  = ws + WS_QP;
  uint8_t*        wpk = ws + WS_WP;
  __hip_bfloat16* fpx = (__hip_bfloat16*)(ws + WS_FPX);
  __hip_bfloat16* wfp = (__hip_bfloat16*)(ws + WS_WFP);
  float*          f1  = (float*)(ws + WS_F1);
  float*          f2  = (float*)(ws + WS_F2);
  float*          f3  = (float*)(ws + WS_F3);

  // fused prep: quant (2048 blocks, 1 wave/token) | conv_w (15360) | conv (1024)
  prep_kernel<<<2048 + 15360 + 1024, 256, 0, stream>>>(
      x, iidx, fidx, int_w, fp_w, qp, wpk, fpx, wfp, f1, f2, f3);
  gemm_kernel<<<(N_TOK / 128) * (OUT_F / 128), 256, 0, stream>>>(
      qp, wpk, fpx, wfp, f1, f2, f3, wsc, red, bias, out);
}